// Round 5
// baseline (232.525 us; speedup 1.0000x reference)
//
#include <hip/hip_runtime.h>

// Shapes: x [32][256][56][56] f32; fc1_w [65][256]; fc2_w [4][65]; fc2_b [4];
//         weight [4][256][256][3][3] f32; bias [4][256]; out [32][256][56][56] f32
//
// ws layout (89,195,008 B):
//  [0)        pooled [32][256] f32                         32768 B
//  [32768)    att    [32][4]  f32                            512 B
//  [33280)    aggb   [32][256] f32                         32768 B
//  [66048)    aggw   [32][2][16][9][128][16] bf16     37,748,736 B   (frag-layout, A read direct)
//  [37814784) xb     [32][3136][256] bf16 (NHWC)      51,380,224 B

typedef short bf16x8 __attribute__((ext_vector_type(8)));
typedef float f32x16 __attribute__((ext_vector_type(16)));

__device__ __forceinline__ unsigned short f2bf(float f) {
  unsigned int u = __float_as_uint(f);
  return (unsigned short)((u + 0x7FFFu + ((u >> 16) & 1u)) >> 16);  // RNE
}
__device__ __forceinline__ float bf2f(unsigned short h) {
  return __uint_as_float(((unsigned int)h) << 16);
}

// ---------------- K1: x NCHW f32 -> NHWC bf16, fused global-avg-pool ----------------
__global__ void xcast_k(const float* __restrict__ x, unsigned short* __restrict__ xb,
                        float* __restrict__ pooled) {
  __shared__ __align__(16) unsigned short tile[64 * 260];  // 64 hw x 256 c (+4 pad)
  int b = blockIdx.y;
  int hw0 = blockIdx.x * 64;   // 49*64 = 3136
  int t = threadIdx.x;
  int lane = t & 63, wq = t >> 6;
#pragma unroll 8
  for (int it = 0; it < 64; ++it) {
    int c = it * 4 + wq;
    float v = x[((size_t)(b * 256 + c)) * 3136 + hw0 + lane];
    tile[lane * 260 + c] = f2bf(v);
  }
  __syncthreads();
  int c4 = lane * 4;
#pragma unroll
  for (int it = 0; it < 16; ++it) {
    int hl = it * 4 + wq;
    ushort4 v = *(const ushort4*)&tile[hl * 260 + c4];
    *(ushort4*)&xb[((size_t)(b * 3136 + hw0 + hl)) * 256 + c4] = v;
  }
  // fused pool: thread t <-> channel t; 2-B lane stride -> conflict-free
  float s = 0.f;
#pragma unroll 16
  for (int hl = 0; hl < 64; ++hl) s += bf2f(tile[hl * 260 + t]);
  atomicAdd(&pooled[b * 256 + t], s * (1.0f / 3136.0f));
}

// ---------------- K2: attention (fc1->relu->fc2->softmax/T) + agg_b ----------------
__global__ void att_k(const float* __restrict__ pooled, const float* __restrict__ fc1,
                      const float* __restrict__ fc2w, const float* __restrict__ fc2b,
                      const float* __restrict__ bias, float* __restrict__ att,
                      float* __restrict__ aggb) {
  int b = blockIdx.x, t = threadIdx.x;   // 64 threads
  __shared__ float p[256];
  __shared__ float h[65];
  __shared__ float a4[4];
  for (int i = t; i < 256; i += 64) p[i] = pooled[b * 256 + i];
  __syncthreads();
  for (int j = t; j < 65; j += 64) {
    float s = 0.f;
    for (int c = 0; c < 256; ++c) s += p[c] * fc1[j * 256 + c];
    h[j] = fmaxf(s, 0.f);
  }
  __syncthreads();
  if (t == 0) {
    float lg[4];
    for (int k = 0; k < 4; ++k) {
      float s = fc2b[k];
      for (int j = 0; j < 65; ++j) s += h[j] * fc2w[k * 65 + j];
      lg[k] = s * (1.0f / 34.0f);
    }
    float m = fmaxf(fmaxf(lg[0], lg[1]), fmaxf(lg[2], lg[3]));
    float e0 = expf(lg[0] - m), e1 = expf(lg[1] - m), e2 = expf(lg[2] - m), e3 = expf(lg[3] - m);
    float inv = 1.0f / (e0 + e1 + e2 + e3);
    a4[0] = e0 * inv; a4[1] = e1 * inv; a4[2] = e2 * inv; a4[3] = e3 * inv;
    for (int k = 0; k < 4; ++k) att[b * 4 + k] = a4[k];
  }
  __syncthreads();
  for (int o = t; o < 256; o += 64) {
    float s = 0.f;
    for (int k = 0; k < 4; ++k) s += a4[k] * bias[k * 256 + o];
    aggb[b * 256 + o] = s;
  }
}

// ---------------- K3: agg_w -> [b][ot2][ic16][r9][ol128][il16] bf16 (A-frag layout) ---
__global__ void aggw_k(const float* __restrict__ weight, const float* __restrict__ att,
                       unsigned short* __restrict__ aggw) {
  __shared__ float wl[4 * 2304];
  int o = blockIdx.x, t = threadIdx.x;   // t = input channel i
  for (int k = 0; k < 4; ++k)
    for (int idx = t; idx < 2304; idx += 256)
      wl[k * 2304 + idx] = weight[((size_t)(k * 256 + o)) * 2304 + idx];
  __syncthreads();
  int ot = o >> 7, ol = o & 127, ic = t >> 4, il = t & 15;
  int b0 = blockIdx.y * 8;
  for (int b = b0; b < b0 + 8; ++b) {
    float a0 = att[b * 4 + 0], a1 = att[b * 4 + 1], a2 = att[b * 4 + 2], a3 = att[b * 4 + 3];
    size_t base = ((size_t)((b * 2 + ot) * 16 + ic)) * (9 * 2048) + ol * 16 + il;
#pragma unroll
    for (int r = 0; r < 9; ++r) {
      float s = a0 * wl[t * 9 + r] + a1 * wl[2304 + t * 9 + r] +
                a2 * wl[4608 + t * 9 + r] + a3 * wl[6912 + t * 9 + r];
      aggw[base + r * 2048] = f2bf(s);
    }
  }
}

// ---------------- K4: per-sample conv, A direct-from-global, X dbuf LDS --------------
// 256 thr (4 waves = 2wo x 2wn). Block tile 128o x 256n; wave tile 64o x 128n
// (2m x 4n frags of 32x32x16). K: 16 chunks of 16 ch.
// LDS: X only, [8 rows][64 cols][16ch] = 16KB, double-buffered (32KB).
// X swizzle (write+read): 32B granule pos, byte ^= (pos&7)<<4.
#define XBUF 16384

__global__ __launch_bounds__(256, 2) void conv_k(const unsigned short* __restrict__ xb,
                                                 const unsigned short* __restrict__ aggw,
                                                 const float* __restrict__ aggb,
                                                 float* __restrict__ out) {
  __shared__ __align__(16) unsigned char lds[2 * XBUF];
  const int t = threadIdx.x;
  const int wid = t >> 6, lane = t & 63, l31 = lane & 31, q = lane >> 5;
  const int wo = wid >> 1, wn = wid & 1;

  // XCD-chunked bijective swizzle: 832 blocks = 8 XCDs x 104; bn fastest within XCD
  int id = blockIdx.x;
  int wgid = (id & 7) * 104 + (id >> 3);
  int bn = wgid % 13;
  int rest = wgid / 13;          // = b*2 + bo
  int b = rest >> 1, bo = rest & 1;

  const int o0 = bo * 128;
  const int n0 = bn * 256;
  const int h0 = n0 / 56;

  // B (X-tile) fragment geometry: 4 n-frags per wave
  int bbase[4], nn[4], swz[4][3];
#pragma unroll
  for (int nf = 0; nf < 4; ++nf) {
    int n = n0 + wn * 128 + nf * 32 + l31;
    int h = n / 56, w = n - h * 56;
    nn[nf] = n;
    bbase[nf] = ((h - h0) * 64 + w) * 32 + q * 16;
#pragma unroll
    for (int dw = 0; dw < 3; ++dw) swz[nf][dw] = ((w + dw) & 7) << 4;
  }
  // A fragment global lane offsets (aggw layout == frag layout)
  int aoff[2];
#pragma unroll
  for (int mf = 0; mf < 2; ++mf) aoff[mf] = (wo * 64 + mf * 32 + l31) * 32 + q * 16;

  // X staging geometry (1024 16B slots, 4/thread)
  int xsrc[4], xdst[4];
#pragma unroll
  for (int j = 0; j < 4; ++j) {
    int idx = j * 256 + t;
    int pos = idx >> 1, sub = idx & 1;
    int row = pos >> 6, col = pos & 63;
    int hg = h0 - 1 + row, wg = col - 1;
    bool valid = (col >= 1 && col <= 56 && hg >= 0 && hg < 56);
    xsrc[j] = valid ? ((hg * 56 + wg) * 512 + sub * 16) : -1;
    xdst[j] = (idx * 16) ^ ((pos & 7) << 4);
  }

  f32x16 acc[2][4];
#pragma unroll
  for (int i = 0; i < 2; ++i)
#pragma unroll
    for (int j = 0; j < 4; ++j)
#pragma unroll
      for (int e = 0; e < 16; ++e) acc[i][j][e] = 0.f;

  const char* xb_b = (const char*)xb + (size_t)b * 3136 * 512;
  const char* ag_c = (const char*)aggw + (size_t)rest * 589824;   // [16 ic][9 r][128 ol][16 il]*2B

  // prologue: stage chunk 0 -> buf 0
#pragma unroll
  for (int j = 0; j < 4; ++j) {
    uint4 v = make_uint4(0u, 0u, 0u, 0u);
    if (xsrc[j] >= 0) v = *(const uint4*)(xb_b + xsrc[j]);
    *(uint4*)(lds + xdst[j]) = v;
  }
  __syncthreads();

  int cur = 0;
  for (int ic = 0; ic < 16; ++ic) {
    // T14: issue next chunk's global loads first (latency hides under compute)
    uint4 nv[4];
    const bool more = (ic + 1 < 16);
    if (more) {
#pragma unroll
      for (int j = 0; j < 4; ++j) {
        uint4 v = make_uint4(0u, 0u, 0u, 0u);
        if (xsrc[j] >= 0) v = *(const uint4*)(xb_b + xsrc[j] + (ic + 1) * 32);
        nv[j] = v;
      }
    }
    const unsigned char* xlds = lds + cur * XBUF;
    const char* agc = ag_c + (size_t)ic * 36864;   // 9 * 4096 B
#pragma unroll
    for (int r = 0; r < 9; ++r) {
      const int dh = r / 3, dw = r % 3;
      bf16x8 a0 = *(const bf16x8*)(agc + r * 4096 + aoff[0]);
      bf16x8 a1 = *(const bf16x8*)(agc + r * 4096 + aoff[1]);
#pragma unroll
      for (int nf = 0; nf < 4; ++nf) {
        bf16x8 bb = *(const bf16x8*)(xlds + ((bbase[nf] + dh * 2048 + dw * 32) ^ swz[nf][dw]));
        acc[0][nf] = __builtin_amdgcn_mfma_f32_32x32x16_bf16(a0, bb, acc[0][nf], 0, 0, 0);
        acc[1][nf] = __builtin_amdgcn_mfma_f32_32x32x16_bf16(a1, bb, acc[1][nf], 0, 0, 0);
      }
    }
    if (more) {
      unsigned char* dst = lds + (cur ^ 1) * XBUF;
#pragma unroll
      for (int j = 0; j < 4; ++j) *(uint4*)(dst + xdst[j]) = nv[j];
      __syncthreads();   // one barrier per chunk
    }
    cur ^= 1;
  }

  // ---- epilogue: D layout col=lane&31 (n), row=(reg&3)+8*(reg>>2)+4*q (o)
#pragma unroll
  for (int mf = 0; mf < 2; ++mf) {
#pragma unroll
    for (int reg = 0; reg < 16; ++reg) {
      int o = o0 + wo * 64 + mf * 32 + (reg & 3) + 8 * (reg >> 2) + 4 * q;
      float ab = aggb[b * 256 + o];
      float* op = out + ((size_t)(b * 256 + o)) * 3136;
#pragma unroll
      for (int nf = 0; nf < 4; ++nf) {
        if (nn[nf] < 3136) op[nn[nf]] = acc[mf][nf][reg] + ab;
      }
    }
  }
}

extern "C" void kernel_launch(void* const* d_in, const int* in_sizes, int n_in,
                              void* d_out, int out_size, void* d_ws, size_t ws_size,
                              hipStream_t stream) {
  const float* x      = (const float*)d_in[0];
  const float* fc1    = (const float*)d_in[1];
  const float* fc2w   = (const float*)d_in[2];
  const float* fc2b   = (const float*)d_in[3];
  const float* weight = (const float*)d_in[4];
  const float* bias   = (const float*)d_in[5];
  float* out = (float*)d_out;

  char* ws = (char*)d_ws;
  float* pooled         = (float*)(ws);
  float* att            = (float*)(ws + 32768);
  float* aggb           = (float*)(ws + 33280);
  unsigned short* aggw  = (unsigned short*)(ws + 66048);
  unsigned short* xb    = (unsigned short*)(ws + 66048 + 37748736);

  hipMemsetAsync(pooled, 0, 32768, stream);          // pooled accumulated via atomics
  xcast_k<<<dim3(49, 32), 256, 0, stream>>>(x, xb, pooled);
  att_k<<<32, 64, 0, stream>>>(pooled, fc1, fc2w, fc2b, bias, att, aggb);
  aggw_k<<<dim3(256, 4), 256, 0, stream>>>(weight, att, aggw);
  conv_k<<<832, 256, 0, stream>>>(xb, aggw, aggb, out);
}